// Round 1
// baseline (2981.216 us; speedup 1.0000x reference)
//
#include <hip/hip_runtime.h>

#define IMG_H 1024
#define IMG_W 1024

constexpr int TW = 58;           // output cols per block (lanes 0..57 valid, 64 ext cols)
constexpr int TH = 64;           // output rows per block
constexpr int CH = 16;           // rows per wave
constexpr int GW = 72, GH = 78;  // guide tile: TW+14 x TH+14
constexpr int XW = 66, XH = 72;  // blended-noisy tile: TW+8 x TH+8

__device__ __forceinline__ int refl(int i) {
  i = (i < 0) ? -i : i;
  return (i >= IMG_H) ? (2 * IMG_H - 2 - i) : i;
}

__global__ __launch_bounds__(256) void nlm_kernel(
    const float* __restrict__ Y, const float* __restrict__ Xp,
    float* __restrict__ Out,
    const float* __restrict__ Harr, int hidx,
    const float* __restrict__ Sarr, int sidx) {
  __shared__ float Gs[GH * GW];
  __shared__ float XBs[XH * XW];

  const int b = blockIdx.z;
  const int ty0 = blockIdx.y * TH;
  const int tx0 = blockIdx.x * TW;
  const int gy0 = ty0 - 7, gx0 = tx0 - 7;
  const int xy0 = ty0 - 4, xx0 = tx0 - 4;

  const float hv = Harr[hidx];
  float stepv = 1.0f;
  if (sidx >= 0) stepv = fminf(fmaxf(Sarr[sidx], 0.6f), 1.0f);
  const float omst = 1.0f - stepv;

  const size_t ib = (size_t)b * (IMG_H * IMG_W);
  const float* __restrict__ Yb = Y + ib;
  const float* __restrict__ Xb = Xp + ib;

  const int tid = threadIdx.y * 64 + threadIdx.x;

  // stage guide tile (reflected coords)
  for (int i = tid; i < GH * GW; i += 256) {
    int u = i / GW, v = i - u * GW;
    Gs[i] = Yb[refl(gy0 + u) * IMG_W + refl(gx0 + v)];
  }
  // stage blended noisy tile xb = (1-step)*x_prev + step*y (reflected coords)
  for (int i = tid; i < XH * XW; i += 256) {
    int u = i / XW, v = i - u * XW;
    int g = refl(xy0 + u) * IMG_W + refl(xx0 + v);
    XBs[i] = omst * Xb[g] + stepv * Yb[g];
  }
  __syncthreads();

  const int lane = threadIdx.x;  // 0..63 : extended column tx0-3+lane
  const int wv = threadIdx.y;    // 0..3
  const int cy0 = ty0 + wv * CH;

  // per-lane reflected column (local into Gs)
  const int lcx = refl(tx0 - 3 + lane) - gx0;

  // per-row reflected rows (local, premultiplied) + t-independent guide center values
  int lryW[CH + 6];
  float Gc[CH + 6];
#pragma unroll
  for (int j = 0; j < CH + 6; ++j) {
    int lr = refl(cy0 - 3 + j) - gy0;
    lryW[j] = lr * GW;
    Gc[j] = Gs[lryW[j] + lcx];
  }

  // per-pixel exp coefficient from Laplacian of xb: w = exp2(S * c), c = -log2e/(49*sigma2)
  const int lpx = lane + 4;
  float cfo[CH], num[CH], den[CH];
#pragma unroll
  for (int r = 0; r < CH; ++r) {
    int lpy = wv * CH + r + 4;
    float cen = XBs[lpy * XW + lpx];
    float lap = XBs[(lpy - 1) * XW + lpx] + XBs[(lpy + 1) * XW + lpx] +
                XBs[lpy * XW + lpx - 1] + XBs[lpy * XW + lpx + 1] - 4.0f * cen;
    float sg = hv * lap;
    float s2 = sg * sg + 1e-8f;
    cfo[r] = -0.029442756956917622f / s2;  // log2(e)/49
    num[r] = 0.0f;
    den[r] = 0.0f;
  }

  const int xbase0 = (wv * CH + 4) * XW + lpx;

#pragma unroll 1
  for (int dy = 0; dy < 9; ++dy) {
#pragma unroll 1
    for (int dx = 0; dx < 9; ++dx) {
      const int goff = (dy - 4) * GW + (dx - 4) + lcx;
      const int xoff = (dy - 4) * XW + (dx - 4) + xbase0;
      float er[6];
      float V = 0.0f;
#pragma unroll
      for (int j = 0; j < 6; ++j) {
        float dd = Gc[j] - Gs[lryW[j] + goff];
        er[j] = dd * dd;
        V += er[j];
      }
#pragma unroll
      for (int r = 0; r < CH; ++r) {
        float dd = Gc[r + 6] - Gs[lryW[r + 6] + goff];
        float en = dd * dd;
        V += en;  // V = sum of E rows r..r+6 at this column
        // horizontal 7-tap across lanes
        float a2 = V + __shfl_down(V, 1);
        float a4 = a2 + __shfl_down(a2, 2);
        float S = a4 + __shfl_down(a2, 4) + __shfl_down(V, 6);
        float wgt = exp2f(S * cfo[r]);
        num[r] = fmaf(wgt, XBs[xoff + r * XW], num[r]);
        den[r] += wgt;
        V -= er[r % 6];
        er[r % 6] = en;
      }
    }
  }

  const int px = tx0 + lane;
  if (lane < TW && px < IMG_W) {
#pragma unroll
    for (int r = 0; r < CH; ++r) {
      Out[ib + (size_t)(cy0 + r) * IMG_W + px] = num[r] / den[r];
    }
  }
}

extern "C" void kernel_launch(void* const* d_in, const int* in_sizes, int n_in,
                              void* d_out, int out_size, void* d_ws, size_t ws_size,
                              hipStream_t stream) {
  const float* Y = (const float*)d_in[0];
  const float* Harr = (const float*)d_in[1];
  const float* Sarr = (const float*)d_in[2];
  float* Out = (float*)d_out;
  float* Ws = (float*)d_ws;

  const int B = in_sizes[0] / (IMG_H * IMG_W);
  dim3 block(64, 4, 1);
  dim3 grid((IMG_W + TW - 1) / TW, IMG_H / TH, B);

  // 4 ping-ponged rounds; final lands in d_out
  nlm_kernel<<<grid, block, 0, stream>>>(Y, Y, Ws, Harr, 0, Sarr, -1);
  nlm_kernel<<<grid, block, 0, stream>>>(Y, Ws, Out, Harr, 1, Sarr, 0);
  nlm_kernel<<<grid, block, 0, stream>>>(Y, Out, Ws, Harr, 2, Sarr, 1);
  nlm_kernel<<<grid, block, 0, stream>>>(Y, Ws, Out, Harr, 3, Sarr, 2);
}

// Round 3
// 2076.746 us; speedup vs baseline: 1.4355x; 1.4355x over previous
//
#include <hip/hip_runtime.h>

#define IMG 1024

constexpr int TW = 122;          // output cols per block (pairs: lanes 0..60)
constexpr int TH = 64;           // output rows per block
constexpr int CH = 16;           // rows per wave (4 waves)
constexpr int GW = TW + 14;      // 136
constexpr int GH = TH + 14;      // 78
constexpr int XW = TW + 8;       // 130
constexpr int XH = TH + 8;       // 72

__device__ __forceinline__ int refl(int i) {
  i = (i < 0) ? -i : i;
  return (i >= IMG) ? (2 * IMG - 2 - i) : i;
}

template <bool AFFINE>
__device__ __forceinline__ void nlm_body(
    const float* __restrict__ Gs, const float* __restrict__ XBs,
    float* __restrict__ Out, size_t ib, int tx0, int ty0, float hv) {
  const int lane = threadIdx.x;            // 0..63
  const int wv = threadIdx.y;              // 0..3
  const int c2 = 2 * lane;                 // ext col pair base, 0..126 (halo lanes included)
  const int cx2 = (c2 > 120) ? 120 : c2;   // clamped col for X-tile reads (halo lanes: dead data, in-bounds)
  const int cy0 = ty0 + wv * CH;
  const int rb0 = (wv * CH + 4) * GW;      // affine local row base (patch row j=0)

  // shifted-term row table (premultiplied); only needed on border blocks
  int lryW[CH + 6];
  if constexpr (!AFFINE) {
#pragma unroll
    for (int j = 0; j < CH + 6; ++j)
      lryW[j] = (refl(cy0 - 3 + j) - (ty0 - 7)) * GW;
  }
  // shifted-term col indices (local): R(m_x) - gx0; tx0 <= IMG-TW guarantees in-tile
  int lc0, lc1;
  if constexpr (AFFINE) {
    lc0 = c2 + 4;
    lc1 = c2 + 5;
  } else {
    lc0 = refl(tx0 - 3 + c2) - (tx0 - 7);
    lc1 = refl(tx0 - 2 + c2) - (tx0 - 7);
  }

  // center guide values y(R(m)): staged tile applies reflection -> affine ALWAYS
  float Gc0[CH + 6], Gc1[CH + 6];
#pragma unroll
  for (int j = 0; j < CH + 6; ++j) {
    int base = rb0 + j * GW + c2 + 4;
    Gc0[j] = Gs[base];
    Gc1[j] = Gs[base + 1];
  }

  // per-pixel exp2 coefficient from Laplacian of blended xb
  float cfo0[CH], cfo1[CH], num0[CH], num1[CH], den0[CH], den1[CH];
  const int xrow0 = (wv * CH + 4) * XW + cx2 + 4;
#pragma unroll
  for (int r = 0; r < CH; ++r) {
    int rb = xrow0 + r * XW;
    float cen0 = XBs[rb], cen1 = XBs[rb + 1];
    float lf = XBs[rb - 1], rt = XBs[rb + 2];
    float lap0 = XBs[rb - XW] + XBs[rb + XW] + lf + cen1 - 4.0f * cen0;
    float lap1 = XBs[rb - XW + 1] + XBs[rb + XW + 1] + cen0 + rt - 4.0f * cen1;
    float sg0 = hv * lap0, sg1 = hv * lap1;
    cfo0[r] = -0.029442756956917622f / (sg0 * sg0 + 1e-8f);  // -log2(e)/49 / s2
    cfo1[r] = -0.029442756956917622f / (sg1 * sg1 + 1e-8f);
    num0[r] = 0.f; num1[r] = 0.f; den0[r] = 0.f; den1[r] = 0.f;
  }

#pragma unroll 1
  for (int dy = 0; dy < 9; ++dy) {
#pragma unroll 1
    for (int dx = 0; dx < 9; ++dx) {
      const int go = (dy - 4) * GW + (dx - 4);
      const int a0 = go + lc0, a1 = go + lc1;
      const int xo = (dy - 4) * XW + (dx - 4) + xrow0;
      float er0[6], er1[6], V0 = 0.f, V1 = 0.f;
#pragma unroll
      for (int j = 0; j < 6; ++j) {
        int rw = AFFINE ? (rb0 + j * GW) : lryW[j];
        float g0 = Gs[rw + a0];
        float g1 = Gs[rw + a1];
        float d0 = Gc0[j] - g0, d1 = Gc1[j] - g1;
        er0[j] = d0 * d0; er1[j] = d1 * d1;
        V0 += er0[j]; V1 += er1[j];
      }
#pragma unroll
      for (int r = 0; r < CH; ++r) {
        int rw = AFFINE ? (rb0 + (r + 6) * GW) : lryW[r + 6];
        float g0 = Gs[rw + a0];
        float g1 = Gs[rw + a1];
        float d0 = Gc0[r + 6] - g0, d1 = Gc1[r + 6] - g1;
        float e0 = d0 * d0, e1 = d1 * d1;
        V0 += e0; V1 += e1;
        // horizontal 7-tap for the two columns via 3 shfls
        float P = V0 + V1;
        float Q = P + __shfl_down(P, 1);
        float T = Q + __shfl_down(Q, 2);
        float S0 = T - __shfl_down(V1, 3);
        float S1 = T - V0;
        float w0 = exp2f(S0 * cfo0[r]);
        float w1 = exp2f(S1 * cfo1[r]);
        float x0 = XBs[xo + r * XW];
        float x1 = XBs[xo + r * XW + 1];
        num0[r] = fmaf(w0, x0, num0[r]); den0[r] += w0;
        num1[r] = fmaf(w1, x1, num1[r]); den1[r] += w1;
        V0 -= er0[r % 6]; er0[r % 6] = e0;
        V1 -= er1[r % 6]; er1[r % 6] = e1;
      }
    }
  }

  const int px0 = tx0 + c2;
  if (lane < 61 && px0 + 1 < IMG) {
#pragma unroll
    for (int r = 0; r < CH; ++r) {
      size_t o = ib + (size_t)(cy0 + r) * IMG + px0;
      Out[o] = num0[r] / den0[r];
      Out[o + 1] = num1[r] / den1[r];
    }
  }
}

__global__ __launch_bounds__(256, 2) void nlm_kernel(
    const float* __restrict__ Y, const float* __restrict__ Xp,
    float* __restrict__ Out,
    const float* __restrict__ Harr, int hidx,
    const float* __restrict__ Sarr, int sidx) {
  __shared__ float Gs[GH * GW];
  __shared__ float XBs[XH * XW];

  const int b = blockIdx.z;
  const int ty0 = blockIdx.y * TH;
  // overlap the last x-block so reflected reads stay inside the staged tile
  int tx0 = blockIdx.x * TW;
  if (tx0 > IMG - TW) tx0 = IMG - TW;
  const int gy0 = ty0 - 7, gx0 = tx0 - 7;
  const int xy0 = ty0 - 4, xx0 = tx0 - 4;

  const float hv = Harr[hidx];
  float stepv = 1.0f;
  if (sidx >= 0) stepv = fminf(fmaxf(Sarr[sidx], 0.6f), 1.0f);
  const float omst = 1.0f - stepv;

  const size_t ib = (size_t)b * (IMG * IMG);
  const float* __restrict__ Yb = Y + ib;
  const float* __restrict__ Xb = Xp + ib;

  const int tid = threadIdx.y * 64 + threadIdx.x;

  // stage guide tile (reflection applied at staging)
  for (int i = tid; i < GH * GW; i += 256) {
    int u = i / GW, v = i - u * GW;
    Gs[i] = Yb[refl(gy0 + u) * IMG + refl(gx0 + v)];
  }
  // stage blended noisy tile xb = (1-step)*x_prev + step*y
  for (int i = tid; i < XH * XW; i += 256) {
    int u = i / XW, v = i - u * XW;
    int g = refl(xy0 + u) * IMG + refl(xx0 + v);
    XBs[i] = omst * Xb[g] + stepv * Yb[g];
  }
  __syncthreads();

  const bool aff = (blockIdx.x > 0) && (blockIdx.x < gridDim.x - 1) &&
                   (blockIdx.y > 0) && (blockIdx.y < gridDim.y - 1);
  if (aff)
    nlm_body<true>(Gs, XBs, Out, ib, tx0, ty0, hv);
  else
    nlm_body<false>(Gs, XBs, Out, ib, tx0, ty0, hv);
}

extern "C" void kernel_launch(void* const* d_in, const int* in_sizes, int n_in,
                              void* d_out, int out_size, void* d_ws, size_t ws_size,
                              hipStream_t stream) {
  const float* Y = (const float*)d_in[0];
  const float* Harr = (const float*)d_in[1];
  const float* Sarr = (const float*)d_in[2];
  float* Out = (float*)d_out;
  float* Ws = (float*)d_ws;

  const int B = in_sizes[0] / (IMG * IMG);
  dim3 block(64, 4, 1);
  dim3 grid((IMG + TW - 1) / TW, IMG / TH, B);

  nlm_kernel<<<grid, block, 0, stream>>>(Y, Y, Ws, Harr, 0, Sarr, -1);
  nlm_kernel<<<grid, block, 0, stream>>>(Y, Ws, Out, Harr, 1, Sarr, 0);
  nlm_kernel<<<grid, block, 0, stream>>>(Y, Out, Ws, Harr, 2, Sarr, 1);
  nlm_kernel<<<grid, block, 0, stream>>>(Y, Ws, Out, Harr, 3, Sarr, 2);
}